// Round 9
// baseline (250.385 us; speedup 1.0000x reference)
//
#include <hip/hip_runtime.h>
#include <math.h>

#define BB 256
#define SS 256
#define NH 4

typedef __attribute__((ext_vector_type(8))) short bfrag;   // 8 bf16 (4 VGPRs)
typedef __attribute__((ext_vector_type(4))) float ffrag;   // 4 fp32 acc

__device__ inline unsigned short f2bf(float x) {
    unsigned u = __float_as_uint(x);
    u += 0x7FFF + ((u >> 16) & 1);          // round-to-nearest-even
    return (unsigned short)(u >> 16);
}
__device__ inline float bf2f(unsigned short h) {
    return __uint_as_float(((unsigned)h) << 16);
}
// Bit-twiddled RNE pack (R4/R7/R8-proven numerics).
__device__ inline unsigned pack2(float a, float b) {
    return (unsigned)f2bf(a) | ((unsigned)f2bf(b) << 16);
}
union FragU { unsigned u[4]; bfrag b; };

// Load 8 consecutive fp32 -> bf16 MFMA frag in-register (same rounding as
// the old k0_cast, so og/Q/K/V numerics are bit-identical to R7/R8).
__device__ inline bfrag cvt8(const float* __restrict__ p) {
    const float4 a = *(const float4*)p;
    const float4 c = *(const float4*)(p + 4);
    FragU fu;
    fu.u[0] = pack2(a.x, a.y);
    fu.u[1] = pack2(a.z, a.w);
    fu.u[2] = pack2(c.x, c.y);
    fu.u[3] = pack2(c.z, c.w);
    return fu.b;
}

// Dynamic-LDS layout (element = unsigned short):
//   Qb  [256][40]  @ 0       (10240)
//   Kb  [256][40]  @ 10240   (10240)
//   Vt  [32][264]  @ 20480   ( 8448)
//   Gb  [256][34]  @ 28928   ( 8704)
//   ogL [256][136] @ 37632   (34816)   <- was the og HBM round-trip
//   mask (f32[256]) @ byte 144896
#define QB_O   0
#define KB_O   10240
#define VT_O   20480
#define GB_O   28928
#define OGL_O  37632
#define MASK_BYTE_OFF 144896
#define DYN_LDS_BYTES 145920

// ---------------------------------------------------------------------------
// k_all: ONE kernel, one block per batch row b, 512 thr = 8 waves.
// R9 mega-fusion: after 4 null rounds on k3 (R4 gather / R7 occupancy / R8
// epilogue — all ±1 µs), the remaining suspects are the INTERFACES: og HBM
// round-trip (60 MB inflated write + 17 MB read), k0 (9 µs), inter-kernel
// flush/launch gaps. This removes all of them structurally.
//   for h in 0..3:  phase A (QKVG proj, R3's 8-wave/32-rows indexing)
//                   phase B (attention, R3 indexing, R7 shuffle machinery)
//                   o*g -> ogL (LDS) instead of og (HBM)
//   proj: out = ogL x Wo^T + bo + addt   (k3's MFMA core, A-frags from ogL)
// X/W/Wo converted fp32->bf16 in-register (cvt8): X[b] fetched ONCE per
// block (all heads local), unlike R5's 4x re-read. TLP unchanged: 8 waves/CU.
// ---------------------------------------------------------------------------
__global__ __launch_bounds__(512, 1) void k_all(
    const float* __restrict__ X,             // fp32 [B][S][128]
    const float* __restrict__ W,             // fp32 [512][128]
    const float* __restrict__ gbias,         // [128]
    const float* __restrict__ mask,          // [B][S] (k-indexed)
    const float* __restrict__ bias,          // [NH][S][S]
    const float* __restrict__ Wo,            // fp32 [128][128]
    const float* __restrict__ bo,            // [128]
    const float* __restrict__ addt,          // [S][B][128] view
    float* __restrict__ out)                 // [S][B][128]
{
    const int b = blockIdx.x;
    const int t = threadIdx.x;
    const int w = t >> 6, lane = t & 63, l15 = lane & 15, quad = lane >> 4;

    extern __shared__ unsigned short smem[];
    unsigned short* Qb  = smem + QB_O;    // [s][c] stride 40
    unsigned short* Kb  = smem + KB_O;    // [s][c] stride 40
    unsigned short* Vt  = smem + VT_O;    // [c][s] stride 264
    unsigned short* Gb  = smem + GB_O;    // [s][c] stride 34
    unsigned short* ogL = smem + OGL_O;   // [s][f] stride 136
    float* maskLds = (float*)((char*)smem + MASK_BYTE_OFF);

    if (t < SS) maskLds[t] = (mask[b * SS + t] - 1.0f) * 1e9f;

    const float qscale = 0.17677669529663687f;  // 1/sqrt(32)

    const int srcA = l15 + ((quad & 1) * 2) * 16;
    const int srcB = srcA + 16;
    const bool hi = (quad >> 1) != 0;

    for (int h = 0; h < NH; ++h) {
        __syncthreads();   // prev head's phase B done (h=0: maskLds visible)

        // ---------------- phase A: QKVG projection for head h -------------
        // wave w owns s-rows [32w, 32w+32) (R3-proven 8-wave indexing).
        bfrag Xf[2][4];    // X rows converted once per head (hoisted off half)
#pragma unroll
        for (int st = 0; st < 2; ++st) {
            const int s = w * 32 + st * 16 + l15;
#pragma unroll
            for (int cc = 0; cc < 4; ++cc)
                Xf[st][cc] = cvt8(X + (size_t)(b * SS + s) * 128 + cc * 32 + quad * 8);
        }
        for (int half = 0; half < 2; ++half) {
            bfrag Wfr[4][4];
#pragma unroll
            for (int f4 = 0; f4 < 4; ++f4) {
                const int floc = (half * 4 + f4) * 16 + l15;        // 0..127
                const int grow = (floc >> 5) * 128 + h * 32 + (floc & 31);
#pragma unroll
                for (int cc = 0; cc < 4; ++cc)
                    Wfr[f4][cc] = cvt8(W + (size_t)grow * 128 + cc * 32 + quad * 8);
            }
#pragma unroll
            for (int st = 0; st < 2; ++st) {
#pragma unroll
                for (int f4 = 0; f4 < 4; ++f4) {
                    ffrag D = {0.f, 0.f, 0.f, 0.f};
#pragma unroll
                    for (int cc = 0; cc < 4; ++cc)
                        D = __builtin_amdgcn_mfma_f32_16x16x32_bf16(Xf[st][cc], Wfr[f4][cc], D, 0, 0, 0);
                    const int ft = half * 4 + f4;
                    const int fcol = ft * 16 + l15;
                    const int srow0 = w * 32 + st * 16 + quad * 4;
                    if (ft < 2) {
#pragma unroll
                        for (int r = 0; r < 4; ++r)
                            Qb[(srow0 + r) * 40 + fcol] = f2bf(D[r] * qscale);
                    } else if (ft < 4) {
#pragma unroll
                        for (int r = 0; r < 4; ++r)
                            Kb[(srow0 + r) * 40 + (fcol - 32)] = f2bf(D[r]);
                    } else if (ft < 6) {
                        const int base = (fcol - 64) * 264 + srow0;
                        *(unsigned*)&Vt[base]     = pack2(D[0], D[1]);
                        *(unsigned*)&Vt[base + 2] = pack2(D[2], D[3]);
                    } else {
                        const int c = fcol - 96;
                        const float gb = gbias[h * 32 + c];
#pragma unroll
                        for (int r = 0; r < 4; ++r) {
                            const float g = 1.0f / (1.0f + __expf(-(D[r] + gb)));
                            Gb[(srow0 + r) * 34 + c] = f2bf(g);
                        }
                    }
                }
            }
        }
        __syncthreads();

        // ---------------- phase B: attention for head h --------------------
        bfrag Vfr[2][8];   // A-frags of V^T
#pragma unroll
        for (int ch = 0; ch < 2; ++ch)
#pragma unroll
            for (int ck = 0; ck < 8; ++ck)
                Vfr[ch][ck] = *(const bfrag*)&Vt[(ch * 16 + l15) * 264 + ck * 32 + quad * 8];

        for (int qq = 0; qq < 2; ++qq) {
            const int q = w * 32 + qq * 16 + l15;
            const bfrag Qfr = *(const bfrag*)&Qb[q * 40 + quad * 8];

            ffrag S[16];
#pragma unroll
            for (int kt = 0; kt < 16; ++kt) {
                const bfrag Kfr = *(const bfrag*)&Kb[(kt * 16 + l15) * 40 + quad * 8];
                const ffrag z = {0.f, 0.f, 0.f, 0.f};
                S[kt] = __builtin_amdgcn_mfma_f32_16x16x32_bf16(Kfr, Qfr, z, 0, 0, 0);
            }

            const float* brow = bias + ((size_t)h * SS + q) * SS;
            float m = -1e30f;
#pragma unroll
            for (int kt = 0; kt < 16; ++kt) {
                const float4 bv = *(const float4*)(brow + kt * 16 + quad * 4);
                const float4 mv = *(const float4*)(maskLds + kt * 16 + quad * 4);
                S[kt][0] += bv.x + mv.x; S[kt][1] += bv.y + mv.y;
                S[kt][2] += bv.z + mv.z; S[kt][3] += bv.w + mv.w;
                m = fmaxf(m, fmaxf(fmaxf(S[kt][0], S[kt][1]), fmaxf(S[kt][2], S[kt][3])));
            }
            m = fmaxf(m, __shfl_xor(m, 16, 64));
            m = fmaxf(m, __shfl_xor(m, 32, 64));

            float l = 0.f;
            unsigned pk[16][2];
#pragma unroll
            for (int kt = 0; kt < 16; ++kt) {
                const float p0 = __expf(S[kt][0] - m);
                const float p1 = __expf(S[kt][1] - m);
                const float p2 = __expf(S[kt][2] - m);
                const float p3 = __expf(S[kt][3] - m);
                l += (p0 + p1) + (p2 + p3);
                pk[kt][0] = pack2(p0, p1);
                pk[kt][1] = pack2(p2, p3);
            }
            l += __shfl_xor(l, 16, 64);
            l += __shfl_xor(l, 32, 64);

            ffrag O[2];
            O[0] = (ffrag){0.f, 0.f, 0.f, 0.f};
            O[1] = (ffrag){0.f, 0.f, 0.f, 0.f};
#pragma unroll
            for (int ck = 0; ck < 8; ++ck) {
                const unsigned a0 = (unsigned)__shfl((int)pk[2 * ck][0],     srcA, 64);
                const unsigned b0 = (unsigned)__shfl((int)pk[2 * ck + 1][0], srcA, 64);
                const unsigned a1 = (unsigned)__shfl((int)pk[2 * ck][1],     srcA, 64);
                const unsigned b1 = (unsigned)__shfl((int)pk[2 * ck + 1][1], srcA, 64);
                const unsigned a2 = (unsigned)__shfl((int)pk[2 * ck][0],     srcB, 64);
                const unsigned b2 = (unsigned)__shfl((int)pk[2 * ck + 1][0], srcB, 64);
                const unsigned a3 = (unsigned)__shfl((int)pk[2 * ck][1],     srcB, 64);
                const unsigned b3 = (unsigned)__shfl((int)pk[2 * ck + 1][1], srcB, 64);
                FragU fu;
                fu.u[0] = hi ? b0 : a0;
                fu.u[1] = hi ? b1 : a1;
                fu.u[2] = hi ? b2 : a2;
                fu.u[3] = hi ? b3 : a3;
                O[0] = __builtin_amdgcn_mfma_f32_16x16x32_bf16(Vfr[0][ck], fu.b, O[0], 0, 0, 0);
                O[1] = __builtin_amdgcn_mfma_f32_16x16x32_bf16(Vfr[1][ck], fu.b, O[1], 0, 0, 0);
            }

            const float invl = 1.0f / l;
            const unsigned short* gr = &Gb[q * 34];
            unsigned* orow = (unsigned*)&ogL[q * 136 + h * 32];   // LDS, not HBM
#pragma unroll
            for (int ch = 0; ch < 2; ++ch) {
                const int c0 = ch * 16 + quad * 4;
                const float v0 = O[ch][0] * invl * bf2f(gr[c0 + 0]);
                const float v1 = O[ch][1] * invl * bf2f(gr[c0 + 1]);
                const float v2 = O[ch][2] * invl * bf2f(gr[c0 + 2]);
                const float v3 = O[ch][3] * invl * bf2f(gr[c0 + 3]);
                orow[(c0 >> 1) + 0] = pack2(v0, v1);
                orow[(c0 >> 1) + 1] = pack2(v2, v3);
            }
        }
    }
    __syncthreads();   // ogL complete (all heads, all rows)

    // ---------------- proj: out = ogL x Wo^T + bo + addt -------------------
    // wave w owns c-tile w (c in [16w, 16w+16)); A-frags from ogL stride 136
    // (identical pattern to R7's k3, proven). Epilogue indexing = R7's.
    const int crow = w * 16 + l15;
    bfrag Wofr[4];
#pragma unroll
    for (int cc = 0; cc < 4; ++cc)
        Wofr[cc] = cvt8(Wo + (size_t)crow * 128 + cc * 32 + quad * 8);
    const float boc = bo[crow];

#pragma unroll
    for (int jt = 0; jt < 16; ++jt) {
        bfrag Ab[4];
#pragma unroll
        for (int cc = 0; cc < 4; ++cc)
            Ab[cc] = *(const bfrag*)&ogL[(jt * 16 + l15) * 136 + cc * 32 + quad * 8];

        ffrag D = {0.f, 0.f, 0.f, 0.f};
#pragma unroll
        for (int cc = 0; cc < 4; ++cc)
            D = __builtin_amdgcn_mfma_f32_16x16x32_bf16(Ab[cc], Wofr[cc], D, 0, 0, 0);

#pragma unroll
        for (int r = 0; r < 4; ++r) {
            const int s = jt * 16 + quad * 4 + r;
            const size_t off = ((size_t)s * BB + b) * 128 + crow;
            out[off] = D[r] + boc + addt[off];
        }
    }
}

extern "C" void kernel_launch(void* const* d_in, const int* in_sizes, int n_in,
                              void* d_out, int out_size, void* d_ws, size_t ws_size,
                              hipStream_t stream) {
    const float* X     = (const float*)d_in[0];  // input_qkv [1,256,256,128]
    const float* mask  = (const float*)d_in[1];  // [1,256,1,1,256]
    const float* bias  = (const float*)d_in[2];  // [1,1,4,256,256]
    const float* addt  = (const float*)d_in[3];  // [1,256,256,128]
    const float* Wqkvg = (const float*)d_in[4];  // [512,128]
    const float* gbias = (const float*)d_in[5];  // [128]
    const float* Wo    = (const float*)d_in[6];  // [128,128]
    const float* bo    = (const float*)d_in[7];  // [128]
    float* out = (float*)d_out;

    // one-time opt-in to >64 KB dynamic LDS (host-side, capture-safe)
    static bool attrDone = false;
    if (!attrDone) {
        hipFuncSetAttribute((const void*)k_all,
                            hipFuncAttributeMaxDynamicSharedMemorySize,
                            DYN_LDS_BYTES);
        attrDone = true;
    }

    k_all<<<BB, 512, DYN_LDS_BYTES, stream>>>(X, Wqkvg, gbias, mask, bias,
                                              Wo, bo, addt, out);
}